// Round 1
// baseline (1954.265 us; speedup 1.0000x reference)
//
#include <hip/hip_runtime.h>
#include <math.h>

#define BSZ 256
#define ENC 128
#define EMBD 128

__device__ __forceinline__ float sigf(float x) { return 1.0f / (1.0f + expf(-x)); }

// ---------------------------------------------------------------------------
// GRU step for one level. Block = 256 threads, 32 rows (row = node*BSZ + b).
// gi = x @ Wih^T + bih ; gh = h0 @ Whh^T + bhh (h0 = 0 at leaves -> gh = bhh)
// r = sig(i_r+h_r); z = sig(i_z+h_z); n = tanh(i_n + r*h_n); h = (1-z)*n + z*h0
// Col chunks {0,1,2} map exactly onto gates {r,z,n}; gate state kept in regs.
// h0 is read from hbuf and h written back in-place (read-before-write per row).
// ---------------------------------------------------------------------------
template <bool HAS_H0>
__global__ __launch_bounds__(256) void gru_kernel(
    const int* __restrict__ tokens, const float* __restrict__ emb,
    const float* __restrict__ Wih, const float* __restrict__ Whh,
    const float* __restrict__ bih, const float* __restrict__ bhh,
    float* __restrict__ hbuf, int lvl_start)
{
    __shared__ float xs[32][128];
    __shared__ float hs[HAS_H0 ? 32 : 1][HAS_H0 ? 128 : 4];
    __shared__ int tok[32];

    const int t = threadIdx.x;
    const int base = blockIdx.x * 32;

    if (t < 32) {
        int row = base + t;
        int node = row >> 8;   // / BSZ
        int b = row & 255;
        tok[t] = tokens[(lvl_start + node) * BSZ + b];
    }
    __syncthreads();
    for (int idx = t; idx < 32 * 128; idx += 256) {
        int rl = idx >> 7, k = idx & 127;
        xs[rl][k] = emb[(size_t)tok[rl] * EMBD + k];
        if (HAS_H0) hs[rl][k] = hbuf[(size_t)(base + rl) * ENC + k];
    }
    __syncthreads();

    const int c  = t & 63;   // col within 128-chunk (and col+64)
    const int rg = t >> 6;   // wave id -> row group
    const int r0 = rg * 8;

    float rv0[8], rv1[8], zv0[8], zv1[8];

    for (int chunk = 0; chunk < 3; ++chunk) {
        const int g0 = chunk * 128 + c;
        const int g1 = g0 + 64;
        float ai0[8], ai1[8], ah0[8], ah1[8];
        #pragma unroll
        for (int r = 0; r < 8; ++r) { ai0[r] = 0.f; ai1[r] = 0.f; ah0[r] = 0.f; ah1[r] = 0.f; }

        const float* wi0p = Wih + (size_t)g0 * 128;
        const float* wi1p = Wih + (size_t)g1 * 128;
        const float* wh0p = Whh + (size_t)g0 * 128;
        const float* wh1p = Whh + (size_t)g1 * 128;

        #pragma unroll 4
        for (int k = 0; k < 128; k += 4) {
            float4 wi0 = *(const float4*)(wi0p + k);
            float4 wi1 = *(const float4*)(wi1p + k);
            float4 wh0 = make_float4(0.f, 0.f, 0.f, 0.f);
            float4 wh1 = make_float4(0.f, 0.f, 0.f, 0.f);
            if (HAS_H0) {
                wh0 = *(const float4*)(wh0p + k);
                wh1 = *(const float4*)(wh1p + k);
            }
            #pragma unroll
            for (int r = 0; r < 8; ++r) {
                float4 xv = *(const float4*)&xs[r0 + r][k];
                ai0[r] += xv.x * wi0.x + xv.y * wi0.y + xv.z * wi0.z + xv.w * wi0.w;
                ai1[r] += xv.x * wi1.x + xv.y * wi1.y + xv.z * wi1.z + xv.w * wi1.w;
                if (HAS_H0) {
                    float4 hv = *(const float4*)&hs[r0 + r][k];
                    ah0[r] += hv.x * wh0.x + hv.y * wh0.y + hv.z * wh0.z + hv.w * wh0.w;
                    ah1[r] += hv.x * wh1.x + hv.y * wh1.y + hv.z * wh1.z + hv.w * wh1.w;
                }
            }
        }

        const float bi0 = bih[g0], bi1 = bih[g1];
        const float bh0 = bhh[g0], bh1 = bhh[g1];

        if (chunk == 0) {
            #pragma unroll
            for (int r = 0; r < 8; ++r) {
                rv0[r] = sigf(bi0 + ai0[r] + bh0 + ah0[r]);
                rv1[r] = sigf(bi1 + ai1[r] + bh1 + ah1[r]);
            }
        } else if (chunk == 1) {
            #pragma unroll
            for (int r = 0; r < 8; ++r) {
                zv0[r] = sigf(bi0 + ai0[r] + bh0 + ah0[r]);
                zv1[r] = sigf(bi1 + ai1[r] + bh1 + ah1[r]);
            }
        } else {
            #pragma unroll
            for (int r = 0; r < 8; ++r) {
                float n0 = tanhf(bi0 + ai0[r] + rv0[r] * (bh0 + ah0[r]));
                float n1 = tanhf(bi1 + ai1[r] + rv1[r] * (bh1 + ah1[r]));
                float hp0 = HAS_H0 ? hs[r0 + r][c] : 0.f;
                float hp1 = HAS_H0 ? hs[r0 + r][c + 64] : 0.f;
                float o0 = (1.f - zv0[r]) * n0 + zv0[r] * hp0;
                float o1 = (1.f - zv1[r]) * n1 + zv1[r] * hp1;
                size_t orow = (size_t)(base + r0 + r) * ENC;
                hbuf[orow + c]      = o0;
                hbuf[orow + c + 64] = o1;
            }
        }
    }
}

// ---------------------------------------------------------------------------
// Child attention -> h0 for one internal level. Block = 256 threads, 8 parent
// rows (32 child rows). u is never materialized: scores computed directly.
// ---------------------------------------------------------------------------
__global__ __launch_bounds__(256) void attn_kernel(
    const float* __restrict__ hch, float* __restrict__ h0out,
    const float* __restrict__ SW, const float* __restrict__ sb,
    const float* __restrict__ cw)
{
    __shared__ float chs[32][128];
    __shared__ float sc[32];
    __shared__ float al[32];

    const int t = threadIdx.x;
    const int base = blockIdx.x * 8;   // parent rows

    for (int idx = t; idx < 32 * 128; idx += 256) {
        int rl = idx >> 7, e = idx & 127;
        int pr = base + (rl >> 2);
        int k = rl & 3;
        int node = pr >> 8, b = pr & 255;
        int cr = (node * 4 + k) * BSZ + b;
        chs[rl][e] = hch[(size_t)cr * ENC + e];
    }
    __syncthreads();

    // scores: wave w handles child rows w*8 .. w*8+7; lane l covers f=l, l+64
    const int w = t >> 6, l = t & 63;
    const float cw0 = cw[l], cw1 = cw[l + 64];
    const float sb0 = sb[l], sb1 = sb[l + 64];
    float acc0[8], acc1[8];
    #pragma unroll
    for (int r = 0; r < 8; ++r) { acc0[r] = sb0; acc1[r] = sb1; }

    #pragma unroll 4
    for (int e = 0; e < 128; ++e) {
        float sw0 = SW[e * 128 + l];
        float sw1 = SW[e * 128 + l + 64];
        #pragma unroll
        for (int r = 0; r < 8; ++r) {
            float ch = chs[w * 8 + r][e];
            acc0[r] += ch * sw0;
            acc1[r] += ch * sw1;
        }
    }
    #pragma unroll
    for (int r = 0; r < 8; ++r) {
        float p = tanhf(acc0[r]) * cw0 + tanhf(acc1[r]) * cw1;
        for (int off = 32; off > 0; off >>= 1) p += __shfl_down(p, off);
        if (l == 0) sc[w * 8 + r] = tanhf(p);
    }
    __syncthreads();

    if (t < 8) {
        float s0 = sc[t * 4], s1 = sc[t * 4 + 1], s2 = sc[t * 4 + 2], s3 = sc[t * 4 + 3];
        float m = fmaxf(fmaxf(s0, s1), fmaxf(s2, s3));
        float e0 = expf(s0 - m), e1 = expf(s1 - m), e2 = expf(s2 - m), e3 = expf(s3 - m);
        float inv = 1.f / (e0 + e1 + e2 + e3);
        al[t * 4] = e0 * inv; al[t * 4 + 1] = e1 * inv;
        al[t * 4 + 2] = e2 * inv; al[t * 4 + 3] = e3 * inv;
    }
    __syncthreads();

    for (int idx = t; idx < 8 * 128; idx += 256) {
        int j = idx >> 7, e = idx & 127;
        float v = al[j * 4] * chs[j * 4][e] + al[j * 4 + 1] * chs[j * 4 + 1][e]
                + al[j * 4 + 2] * chs[j * 4 + 2][e] + al[j * 4 + 3] * chs[j * 4 + 3][e];
        h0out[(size_t)(base + j) * ENC + e] = v;
    }
}

// ---------------------------------------------------------------------------
// Running max over nodes of one level into out (B*ENC = 32768 elems).
// h[(n*BSZ+b)*ENC+e] = h[n*32768 + be], be = b*128+e = out index.
// ---------------------------------------------------------------------------
__global__ __launch_bounds__(256) void max_kernel(
    const float* __restrict__ h, int nodes, float* __restrict__ out, int first)
{
    int be = blockIdx.x * blockDim.x + threadIdx.x;
    float v = -INFINITY;
    #pragma unroll 8
    for (int n = 0; n < nodes; ++n)
        v = fmaxf(v, h[(size_t)n * 32768 + be]);
    if (!first) v = fmaxf(v, out[be]);
    out[be] = v;
}

extern "C" void kernel_launch(void* const* d_in, const int* in_sizes, int n_in,
                              void* d_out, int out_size, void* d_ws, size_t ws_size,
                              hipStream_t stream)
{
    const int*   tokens = (const int*)d_in[0];
    const float* emb    = (const float*)d_in[1];
    const float* Wih    = (const float*)d_in[2];
    const float* Whh    = (const float*)d_in[3];
    const float* bih    = (const float*)d_in[4];
    const float* bhh    = (const float*)d_in[5];
    const float* SW     = (const float*)d_in[6];
    const float* sb     = (const float*)d_in[7];
    const float* cw     = (const float*)d_in[8];
    float* out = (float*)d_out;

    // ws: ping-pong level h buffers. bufA holds levels 5,3,1 (max 262144 rows),
    // bufB holds levels 4,2,0 (max 65536 rows). 167.8 MB total.
    float* bufA = (float*)d_ws;
    float* bufB = bufA + (size_t)262144 * 128;

    const int starts[6] = {0, 1, 5, 21, 85, 341};
    const int nsz[6]    = {1, 4, 16, 64, 256, 1024};
    float* buf[6];
    for (int d = 0; d < 6; ++d) buf[d] = ((5 - d) & 1) ? bufB : bufA;

    // leaf level d=5 (h0 = 0)
    {
        int rows = nsz[5] * BSZ;
        gru_kernel<false><<<rows / 32, 256, 0, stream>>>(
            tokens, emb, Wih, Whh, bih, bhh, buf[5], starts[5]);
        max_kernel<<<128, 256, 0, stream>>>(buf[5], nsz[5], out, 1);
    }
    // internal levels d=4..0
    for (int d = 4; d >= 0; --d) {
        int rows = nsz[d] * BSZ;
        attn_kernel<<<rows / 8, 256, 0, stream>>>(buf[d + 1], buf[d], SW, sb, cw);
        gru_kernel<true><<<rows / 32, 256, 0, stream>>>(
            tokens, emb, Wih, Whh, bih, bhh, buf[d], starts[d]);
        max_kernel<<<128, 256, 0, stream>>>(buf[d], nsz[d], out, 0);
    }
}

// Round 2
// 801.833 us; speedup vs baseline: 2.4372x; 2.4372x over previous
//
#include <hip/hip_runtime.h>
#include <math.h>

#define BSZ 256
#define ENC 128

typedef short s8 __attribute__((ext_vector_type(8)));   // 8 bf16 in 4 VGPRs
typedef float f4 __attribute__((ext_vector_type(4)));   // MFMA 16x16 acc

__device__ __forceinline__ float sigf(float x) { return 1.0f / (1.0f + expf(-x)); }

__device__ __forceinline__ unsigned short f2b(float f) {
    unsigned u = __float_as_uint(f);
    u = (u + 0x7FFF + ((u >> 16) & 1)) >> 16;   // RNE
    return (unsigned short)u;
}
__device__ __forceinline__ float b2f(unsigned short b) {
    return __uint_as_float(((unsigned)b) << 16);
}

// ---------------------------------------------------------------------------
// Convert emb / Wih / Whh / SW^T to bf16 (ws is re-poisoned every launch).
// ---------------------------------------------------------------------------
#define EMB_N   6400000          // 50000*128
#define W_N     49152            // 384*128
#define SW_N    16384            // 128*128
__global__ __launch_bounds__(256) void cvt_kernel(
    const float* __restrict__ emb, const float* __restrict__ wih,
    const float* __restrict__ whh, const float* __restrict__ sw,
    unsigned short* __restrict__ embb, unsigned short* __restrict__ wihb,
    unsigned short* __restrict__ whhb, unsigned short* __restrict__ swtb)
{
    int i = blockIdx.x * 256 + threadIdx.x;
    if (i < EMB_N) {
        embb[i] = f2b(emb[i]);
    } else if (i < EMB_N + W_N) {
        int j = i - EMB_N; wihb[j] = f2b(wih[j]);
    } else if (i < EMB_N + 2 * W_N) {
        int j = i - EMB_N - W_N; whhb[j] = f2b(whh[j]);
    } else if (i < EMB_N + 2 * W_N + SW_N) {
        int j = i - EMB_N - 2 * W_N;
        int f = j >> 7, e = j & 127;
        swtb[j] = f2b(sw[e * 128 + f]);     // transpose: SWt[f][e]
    }
}

// ---------------------------------------------------------------------------
// MFMA GRU step. Block = 256 thr (4 waves), 64 rows; wave = 16 rows x 384 cols.
// Layouts (verified m89/m91/m120): A[m=lane&15][k=quad*8+j]; B[k=quad*8+j][n=lane&15];
// C/D col=lane&15, row=quad*4+reg. Gate tiles: r=0..7, z=8..15, n=16..23.
// h0.Whh accumulated into same acc for r,z; separate acc for n (r*h_n term).
// ---------------------------------------------------------------------------
template <bool HAS_H0>
__global__ __launch_bounds__(256, 2) void gru_mfma(
    const int* __restrict__ tokens, const unsigned short* __restrict__ embb,
    const unsigned short* __restrict__ wihb, const unsigned short* __restrict__ whhb,
    const float* __restrict__ bih, const float* __restrict__ bhh,
    const unsigned short* __restrict__ h0buf, unsigned short* __restrict__ hbuf,
    int lvl_start)
{
    __shared__ unsigned short xs[64 * 136];                     // +8 pad: 2-way free
    __shared__ unsigned short hs[HAS_H0 ? 64 * 136 : 8];

    const int t = threadIdx.x;
    const int base = blockIdx.x * 64;

    // stage: 4 threads per row, 32 cols each (4 x 16B)
    {
        int rl = t >> 2, c0 = (t & 3) * 32;
        int row = base + rl;
        int tok = tokens[(lvl_start + (row >> 8)) * BSZ + (row & 255)];
        const unsigned short* src = embb + (size_t)tok * 128 + c0;
        unsigned short* dst = &xs[rl * 136 + c0];
        #pragma unroll
        for (int i = 0; i < 4; ++i) *(s8*)(dst + 8 * i) = *(const s8*)(src + 8 * i);
        if (HAS_H0) {
            const unsigned short* hsrc = h0buf + (size_t)row * 128 + c0;
            unsigned short* hdst = &hs[rl * 136 + c0];
            #pragma unroll
            for (int i = 0; i < 4; ++i) *(s8*)(hdst + 8 * i) = *(const s8*)(hsrc + 8 * i);
        }
    }
    __syncthreads();

    const int lane = t & 63, wv = t >> 6;
    const int quad = lane >> 4, bcol = lane & 15;
    const int mrow = wv * 16 + bcol;

    s8 ax[4], ah[4];
    {
        const unsigned short* axp = &xs[mrow * 136 + quad * 8];
        #pragma unroll
        for (int s = 0; s < 4; ++s) ax[s] = *(const s8*)(axp + 32 * s);
        if (HAS_H0) {
            const unsigned short* ahp = &hs[mrow * 136 + quad * 8];
            #pragma unroll
            for (int s = 0; s < 4; ++s) ah[s] = *(const s8*)(ahp + 32 * s);
        }
    }

    f4 accR[8], accZ[8], accN[8], accNh[8];
    #pragma unroll
    for (int i = 0; i < 8; ++i) {
        accR[i] = (f4)0.f; accZ[i] = (f4)0.f; accN[i] = (f4)0.f; accNh[i] = (f4)0.f;
    }

    const size_t wbase = (size_t)bcol * 128 + quad * 8;
    // x pass: r,z,n
    #pragma unroll
    for (int s = 0; s < 4; ++s) {
        s8 a = ax[s];
        const unsigned short* wp = wihb + wbase + 32 * s;
        #pragma unroll
        for (int tt = 0; tt < 8; ++tt) {
            s8 bR = *(const s8*)(wp + (size_t)(16 * tt) * 128);
            s8 bZ = *(const s8*)(wp + (size_t)(128 + 16 * tt) * 128);
            s8 bN = *(const s8*)(wp + (size_t)(256 + 16 * tt) * 128);
            accR[tt] = __builtin_amdgcn_mfma_f32_16x16x32_bf16(a, bR, accR[tt], 0, 0, 0);
            accZ[tt] = __builtin_amdgcn_mfma_f32_16x16x32_bf16(a, bZ, accZ[tt], 0, 0, 0);
            accN[tt] = __builtin_amdgcn_mfma_f32_16x16x32_bf16(a, bN, accN[tt], 0, 0, 0);
        }
    }
    if (HAS_H0) {
        #pragma unroll
        for (int s = 0; s < 4; ++s) {
            s8 a = ah[s];
            const unsigned short* wp = whhb + wbase + 32 * s;
            #pragma unroll
            for (int tt = 0; tt < 8; ++tt) {
                s8 bR = *(const s8*)(wp + (size_t)(16 * tt) * 128);
                s8 bZ = *(const s8*)(wp + (size_t)(128 + 16 * tt) * 128);
                s8 bN = *(const s8*)(wp + (size_t)(256 + 16 * tt) * 128);
                accR[tt] = __builtin_amdgcn_mfma_f32_16x16x32_bf16(a, bR, accR[tt], 0, 0, 0);
                accZ[tt] = __builtin_amdgcn_mfma_f32_16x16x32_bf16(a, bZ, accZ[tt], 0, 0, 0);
                accNh[tt] = __builtin_amdgcn_mfma_f32_16x16x32_bf16(a, bN, accNh[tt], 0, 0, 0);
            }
        }
    }

    // epilogue: gates + output (bf16)
    #pragma unroll
    for (int tt = 0; tt < 8; ++tt) {
        int g = 16 * tt + bcol;                      // gate-relative col
        float bR = bih[g] + bhh[g];
        float bZ = bih[128 + g] + bhh[128 + g];
        float biN = bih[256 + g], bhN = bhh[256 + g];
        #pragma unroll
        for (int r = 0; r < 4; ++r) {
            int ml = wv * 16 + quad * 4 + r;
            float rr = sigf(accR[tt][r] + bR);
            float zz = sigf(accZ[tt][r] + bZ);
            float hn = HAS_H0 ? (accNh[tt][r] + bhN) : bhN;
            float nn = tanhf(accN[tt][r] + biN + rr * hn);
            float h0v = HAS_H0 ? b2f(hs[ml * 136 + g]) : 0.f;
            float h = (1.f - zz) * nn + zz * h0v;
            hbuf[(size_t)(base + ml) * 128 + g] = f2b(h);
        }
    }
}

// ---------------------------------------------------------------------------
// MFMA attention. Block = 16 parent rows (64 child rows); wave w = sibling k=w.
// u = ch @ SW via MFMA; score = tanh(sum_f tanh(u+sb)*cw) reduced across the
// 16 lanes of each quad; softmax over k; h0 = sum_k alpha*ch -> bf16.
// ---------------------------------------------------------------------------
__global__ __launch_bounds__(256, 2) void attn_mfma(
    const unsigned short* __restrict__ hch, unsigned short* __restrict__ h0out,
    const unsigned short* __restrict__ swt, const float* __restrict__ sb,
    const float* __restrict__ cw)
{
    __shared__ unsigned short chs[64 * 136];
    __shared__ float sc[4][16];
    __shared__ float al[4][16];

    const int t = threadIdx.x;
    const int pbase = blockIdx.x * 16;
    const int pnode = pbase >> 8;
    const int b0 = pbase & 255;

    {
        int lr = t >> 2, c0 = (t & 3) * 32;
        int k = lr >> 4, bl = lr & 15;
        size_t crow = (size_t)((4 * pnode + k) * BSZ + b0 + bl);
        const unsigned short* src = hch + crow * 128 + c0;
        unsigned short* dst = &chs[lr * 136 + c0];
        #pragma unroll
        for (int i = 0; i < 4; ++i) *(s8*)(dst + 8 * i) = *(const s8*)(src + 8 * i);
    }
    __syncthreads();

    const int lane = t & 63, wv = t >> 6;
    const int quad = lane >> 4, bcol = lane & 15;

    s8 a[4];
    {
        const unsigned short* ap = &chs[(wv * 16 + bcol) * 136 + quad * 8];
        #pragma unroll
        for (int s = 0; s < 4; ++s) a[s] = *(const s8*)(ap + 32 * s);
    }

    f4 acc[8];
    #pragma unroll
    for (int i = 0; i < 8; ++i) acc[i] = (f4)0.f;

    const unsigned short* wb = swt + (size_t)bcol * 128 + quad * 8;
    #pragma unroll
    for (int s = 0; s < 4; ++s) {
        #pragma unroll
        for (int tt = 0; tt < 8; ++tt) {
            s8 b = *(const s8*)(wb + (size_t)(16 * tt) * 128 + 32 * s);
            acc[tt] = __builtin_amdgcn_mfma_f32_16x16x32_bf16(a[s], b, acc[tt], 0, 0, 0);
        }
    }

    float part[4] = {0.f, 0.f, 0.f, 0.f};
    #pragma unroll
    for (int tt = 0; tt < 8; ++tt) {
        int f = 16 * tt + bcol;
        float cwf = cw[f], sbf = sb[f];
        #pragma unroll
        for (int r = 0; r < 4; ++r)
            part[r] += tanhf(acc[tt][r] + sbf) * cwf;
    }
    #pragma unroll
    for (int m = 1; m < 16; m <<= 1) {
        #pragma unroll
        for (int r = 0; r < 4; ++r) part[r] += __shfl_xor(part[r], m);
    }
    if (bcol == 0) {
        #pragma unroll
        for (int r = 0; r < 4; ++r) sc[wv][quad * 4 + r] = tanhf(part[r]);
    }
    __syncthreads();

    if (t < 16) {
        float s0 = sc[0][t], s1 = sc[1][t], s2 = sc[2][t], s3 = sc[3][t];
        float m = fmaxf(fmaxf(s0, s1), fmaxf(s2, s3));
        float e0 = expf(s0 - m), e1 = expf(s1 - m), e2 = expf(s2 - m), e3 = expf(s3 - m);
        float inv = 1.f / (e0 + e1 + e2 + e3);
        al[0][t] = e0 * inv; al[1][t] = e1 * inv; al[2][t] = e2 * inv; al[3][t] = e3 * inv;
    }
    __syncthreads();

    {
        int bl = t >> 4, e0 = (t & 15) * 8;
        float a0 = al[0][bl], a1 = al[1][bl], a2 = al[2][bl], a3 = al[3][bl];
        unsigned short outv[8];
        #pragma unroll
        for (int j = 0; j < 8; ++j) {
            int e = e0 + j;
            float v = a0 * b2f(chs[(0 * 16 + bl) * 136 + e])
                    + a1 * b2f(chs[(1 * 16 + bl) * 136 + e])
                    + a2 * b2f(chs[(2 * 16 + bl) * 136 + e])
                    + a3 * b2f(chs[(3 * 16 + bl) * 136 + e]);
            outv[j] = f2b(v);
        }
        *(s8*)(h0out + (size_t)(pbase + bl) * 128 + e0) = *(const s8*)outv;
    }
}

// ---------------------------------------------------------------------------
// Running max over nodes (bf16 h -> fp32 out). 4096 threads x 8 elems (16B loads).
// ---------------------------------------------------------------------------
__global__ __launch_bounds__(256) void max_kernel(
    const unsigned short* __restrict__ h, int nodes, float* __restrict__ out, int first)
{
    int idx = blockIdx.x * 256 + threadIdx.x;
    int e0 = idx * 8;
    float v[8];
    if (first) {
        #pragma unroll
        for (int j = 0; j < 8; ++j) v[j] = -INFINITY;
    } else {
        #pragma unroll
        for (int j = 0; j < 8; ++j) v[j] = out[e0 + j];
    }
    #pragma unroll 4
    for (int n = 0; n < nodes; ++n) {
        s8 hv = *(const s8*)(h + (size_t)n * 32768 + e0);
        #pragma unroll
        for (int j = 0; j < 8; ++j) v[j] = fmaxf(v[j], b2f((unsigned short)hv[j]));
    }
    #pragma unroll
    for (int j = 0; j < 8; ++j) out[e0 + j] = v[j];
}

extern "C" void kernel_launch(void* const* d_in, const int* in_sizes, int n_in,
                              void* d_out, int out_size, void* d_ws, size_t ws_size,
                              hipStream_t stream)
{
    const int*   tokens = (const int*)d_in[0];
    const float* emb    = (const float*)d_in[1];
    const float* Wih    = (const float*)d_in[2];
    const float* Whh    = (const float*)d_in[3];
    const float* bih    = (const float*)d_in[4];
    const float* bhh    = (const float*)d_in[5];
    const float* SW     = (const float*)d_in[6];
    const float* sb     = (const float*)d_in[7];
    const float* cw     = (const float*)d_in[8];
    float* out = (float*)d_out;

    // ws layout (bf16 buffers, 16B-aligned)
    unsigned short* embb = (unsigned short*)d_ws;                    // 12.8 MB
    unsigned short* wihb = embb + (size_t)EMB_N;                     // 96 KB
    unsigned short* whhb = wihb + W_N;                               // 96 KB
    unsigned short* swtb = whhb + W_N;                               // 32 KB
    unsigned short* bufA = swtb + SW_N;                              // 67.1 MB (levels 5,3,1)
    unsigned short* bufB = bufA + (size_t)262144 * 128;              // 16.8 MB (levels 4,2,0)
    unsigned short* h0b  = bufB + (size_t)65536 * 128;               // 16.8 MB

    const int starts[6] = {0, 1, 5, 21, 85, 341};
    const int nsz[6]    = {1, 4, 16, 64, 256, 1024};
    unsigned short* buf[6];
    for (int d = 0; d < 6; ++d) buf[d] = ((5 - d) & 1) ? bufB : bufA;

    cvt_kernel<<<(EMB_N + 2 * W_N + SW_N + 255) / 256, 256, 0, stream>>>(
        emb, Wih, Whh, SW, embb, wihb, whhb, swtb);

    // leaf level d=5 (h0 = 0)
    {
        int rows = nsz[5] * BSZ;
        gru_mfma<false><<<rows / 64, 256, 0, stream>>>(
            tokens, embb, wihb, whhb, bih, bhh, nullptr, buf[5], starts[5]);
        max_kernel<<<16, 256, 0, stream>>>(buf[5], nsz[5], out, 1);
    }
    // internal levels d=4..0
    for (int d = 4; d >= 0; --d) {
        int rows = nsz[d] * BSZ;
        attn_mfma<<<rows / 16, 256, 0, stream>>>(buf[d + 1], h0b, swtb, sb, cw);
        gru_mfma<true><<<rows / 64, 256, 0, stream>>>(
            tokens, embb, wihb, whhb, bih, bhh, h0b, buf[d], starts[d]);
        max_kernel<<<16, 256, 0, stream>>>(buf[d], nsz[d], out, 0);
    }
}

// Round 3
// 408.279 us; speedup vs baseline: 4.7866x; 1.9639x over previous
//
#include <hip/hip_runtime.h>
#include <math.h>

#define BSZ 256
#define ENC 128

typedef short s8 __attribute__((ext_vector_type(8)));   // 8 bf16 in 4 VGPRs
typedef float f4 __attribute__((ext_vector_type(4)));   // MFMA 16x16 acc
typedef unsigned short ushort_t;

__device__ __forceinline__ float sigf(float x) { return 1.0f / (1.0f + expf(-x)); }

__device__ __forceinline__ ushort_t f2b(float f) {
    unsigned u = __float_as_uint(f);
    u = (u + 0x7FFF + ((u >> 16) & 1)) >> 16;   // RNE
    return (ushort_t)u;
}
__device__ __forceinline__ float b2f(ushort_t b) {
    return __uint_as_float(((unsigned)b) << 16);
}

// ---------------------------------------------------------------------------
// Convert emb / Wih / Whh / SW^T to bf16, 4 elems/thread.
// ---------------------------------------------------------------------------
#define EMB_N   6400000          // 50000*128
#define W_N     49152            // 384*128
#define SW_N    16384            // 128*128
#define CVT_N   (EMB_N + 2 * W_N + SW_N)

__global__ __launch_bounds__(256) void cvt_kernel(
    const float* __restrict__ emb, const float* __restrict__ wih,
    const float* __restrict__ whh, const float* __restrict__ sw,
    ushort_t* __restrict__ embb, ushort_t* __restrict__ wihb,
    ushort_t* __restrict__ whhb, ushort_t* __restrict__ swtb)
{
    int i = (blockIdx.x * 256 + threadIdx.x) * 4;
    if (i >= CVT_N) return;
    if (i < EMB_N) {
        float4 v = *(const float4*)(emb + i);
        short4 o; o.x = f2b(v.x); o.y = f2b(v.y); o.z = f2b(v.z); o.w = f2b(v.w);
        *(short4*)(embb + i) = o;
    } else if (i < EMB_N + W_N) {
        int j = i - EMB_N;
        float4 v = *(const float4*)(wih + j);
        short4 o; o.x = f2b(v.x); o.y = f2b(v.y); o.z = f2b(v.z); o.w = f2b(v.w);
        *(short4*)(wihb + j) = o;
    } else if (i < EMB_N + 2 * W_N) {
        int j = i - EMB_N - W_N;
        float4 v = *(const float4*)(whh + j);
        short4 o; o.x = f2b(v.x); o.y = f2b(v.y); o.z = f2b(v.z); o.w = f2b(v.w);
        *(short4*)(whhb + j) = o;
    } else {
        int j = i - EMB_N - 2 * W_N;
        int f = j >> 7, e0 = j & 127;
        short4 o;
        o.x = f2b(sw[(e0 + 0) * 128 + f]);
        o.y = f2b(sw[(e0 + 1) * 128 + f]);
        o.z = f2b(sw[(e0 + 2) * 128 + f]);
        o.w = f2b(sw[(e0 + 3) * 128 + f]);
        *(short4*)(swtb + j) = o;        // SWt[f][e]
    }
}

// ---------------------------------------------------------------------------
// GRU step. Block = 512 thr (8 waves), 128 rows. Wave w owns gate-cols
// w*16..w*16+15 for ALL gates; its B-fragments (Wih + Whh) live in registers
// for the whole block (amortized over 8 M-tiles). x staged in LDS; h0 A-frags
// and epilogue h0 read directly from global (L1-resident per-block tile).
// Layouts (verified): A[m=lane&15][k=quad*8+j]; C/D col=lane&15, row=quad*4+reg.
// ---------------------------------------------------------------------------
template <bool HAS_H0>
__global__ __launch_bounds__(512) void gru_mfma(
    const int* __restrict__ tokens, const ushort_t* __restrict__ embb,
    const ushort_t* __restrict__ wihb, const ushort_t* __restrict__ whhb,
    const float* __restrict__ bih, const float* __restrict__ bhh,
    const ushort_t* __restrict__ h0buf, ushort_t* __restrict__ hbuf,
    int lvl_start)
{
    __shared__ ushort_t xs[128 * 136];   // stride 136: conflict-free b128

    const int t = threadIdx.x;
    const int base = blockIdx.x * 128;

    // stage x: 4 threads per row, 32 shorts each
    {
        int rl = t >> 2, c0 = (t & 3) * 32;
        int row = base + rl;
        int tok = tokens[(lvl_start + (row >> 8)) * BSZ + (row & 255)];
        const ushort_t* src = embb + (size_t)tok * 128 + c0;
        ushort_t* dst = &xs[rl * 136 + c0];
        #pragma unroll
        for (int i = 0; i < 4; ++i) *(s8*)(dst + 8 * i) = *(const s8*)(src + 8 * i);
    }

    const int lane = t & 63, w = t >> 6;
    const int quad = lane >> 4, bcol = lane & 15;
    const int g = w * 16 + bcol;                  // this lane's gate-col

    // B fragments in registers (loaded once per block)
    s8 bwi[3][4], bwh[3][4];
    #pragma unroll
    for (int gm = 0; gm < 3; ++gm) {
        const ushort_t* wp = wihb + (size_t)(gm * 128 + g) * 128 + quad * 8;
        #pragma unroll
        for (int s = 0; s < 4; ++s) bwi[gm][s] = *(const s8*)(wp + 32 * s);
    }
    if (HAS_H0) {
        #pragma unroll
        for (int gm = 0; gm < 3; ++gm) {
            const ushort_t* wp = whhb + (size_t)(gm * 128 + g) * 128 + quad * 8;
            #pragma unroll
            for (int s = 0; s < 4; ++s) bwh[gm][s] = *(const s8*)(wp + 32 * s);
        }
    }

    const float bR  = bih[g] + bhh[g];
    const float bZ  = bih[128 + g] + bhh[128 + g];
    const float biN = bih[256 + g];
    const float bhN = bhh[256 + g];

    __syncthreads();

    for (int mt = 0; mt < 8; ++mt) {
        s8 ax[4], ah[4];
        {
            const ushort_t* ap = &xs[(mt * 16 + bcol) * 136 + quad * 8];
            #pragma unroll
            for (int s = 0; s < 4; ++s) ax[s] = *(const s8*)(ap + 32 * s);
            if (HAS_H0) {
                const ushort_t* hp = h0buf + (size_t)(base + mt * 16 + bcol) * 128 + quad * 8;
                #pragma unroll
                for (int s = 0; s < 4; ++s) ah[s] = *(const s8*)(hp + 32 * s);
            }
        }

        f4 accR = (f4)0.f, accZ = (f4)0.f, accN = (f4)0.f, accNh = (f4)0.f;
        #pragma unroll
        for (int s = 0; s < 4; ++s) {
            accR = __builtin_amdgcn_mfma_f32_16x16x32_bf16(ax[s], bwi[0][s], accR, 0, 0, 0);
            accZ = __builtin_amdgcn_mfma_f32_16x16x32_bf16(ax[s], bwi[1][s], accZ, 0, 0, 0);
            accN = __builtin_amdgcn_mfma_f32_16x16x32_bf16(ax[s], bwi[2][s], accN, 0, 0, 0);
        }
        if (HAS_H0) {
            #pragma unroll
            for (int s = 0; s < 4; ++s) {
                accR  = __builtin_amdgcn_mfma_f32_16x16x32_bf16(ah[s], bwh[0][s], accR, 0, 0, 0);
                accZ  = __builtin_amdgcn_mfma_f32_16x16x32_bf16(ah[s], bwh[1][s], accZ, 0, 0, 0);
                accNh = __builtin_amdgcn_mfma_f32_16x16x32_bf16(ah[s], bwh[2][s], accNh, 0, 0, 0);
            }
        }

        #pragma unroll
        for (int r = 0; r < 4; ++r) {
            int mrow = mt * 16 + quad * 4 + r;
            float rr = sigf(accR[r] + bR);
            float zz = sigf(accZ[r] + bZ);
            float hn = HAS_H0 ? (accNh[r] + bhN) : bhN;
            float nn = tanhf(accN[r] + biN + rr * hn);
            float h0v = HAS_H0 ? b2f(h0buf[(size_t)(base + mrow) * 128 + g]) : 0.f;
            float h = (1.f - zz) * nn + zz * h0v;
            hbuf[(size_t)(base + mrow) * 128 + g] = f2b(h);
        }
    }
}

// ---------------------------------------------------------------------------
// Attention. Block = 512 thr (8 waves), 32 parents (128 child rows). Wave w
// owns u-cols w*16..+15 with SW fragments in registers; per-wave partial
// scores combined across waves in LDS; softmax over k; h0 -> bf16.
// ---------------------------------------------------------------------------
__global__ __launch_bounds__(512) void attn_mfma(
    const ushort_t* __restrict__ hch, ushort_t* __restrict__ h0out,
    const ushort_t* __restrict__ swt, const float* __restrict__ sb,
    const float* __restrict__ cw)
{
    __shared__ ushort_t chs[128 * 136];
    __shared__ float scp[8][128];
    __shared__ float sc[128];
    __shared__ float al[4][32];

    const int t = threadIdx.x;
    const int pbase = blockIdx.x * 32;
    const int pnode = pbase >> 8;
    const int b0 = pbase & 255;

    // stage 128 child rows (k-major: lr = k*32 + bl)
    {
        int lr = t >> 2, c0 = (t & 3) * 32;
        int k = lr >> 5, bl = lr & 31;
        const ushort_t* src = hch + ((size_t)(4 * pnode + k) * BSZ + b0 + bl) * 128 + c0;
        ushort_t* dst = &chs[lr * 136 + c0];
        #pragma unroll
        for (int i = 0; i < 4; ++i) *(s8*)(dst + 8 * i) = *(const s8*)(src + 8 * i);
    }

    const int lane = t & 63, w = t >> 6;
    const int quad = lane >> 4, bcol = lane & 15;
    const int f = w * 16 + bcol;
    const float cwf = cw[f], sbf = sb[f];

    s8 bsw[4];
    {
        const ushort_t* wp = swt + (size_t)f * 128 + quad * 8;
        #pragma unroll
        for (int s = 0; s < 4; ++s) bsw[s] = *(const s8*)(wp + 32 * s);
    }
    __syncthreads();

    for (int mt = 0; mt < 8; ++mt) {
        s8 a[4];
        const ushort_t* ap = &chs[(mt * 16 + bcol) * 136 + quad * 8];
        #pragma unroll
        for (int s = 0; s < 4; ++s) a[s] = *(const s8*)(ap + 32 * s);

        f4 acc = (f4)0.f;
        #pragma unroll
        for (int s = 0; s < 4; ++s)
            acc = __builtin_amdgcn_mfma_f32_16x16x32_bf16(a[s], bsw[s], acc, 0, 0, 0);

        float part[4];
        #pragma unroll
        for (int r = 0; r < 4; ++r) part[r] = tanhf(acc[r] + sbf) * cwf;
        #pragma unroll
        for (int m = 1; m < 16; m <<= 1) {
            #pragma unroll
            for (int r = 0; r < 4; ++r) part[r] += __shfl_xor(part[r], m);
        }
        if (bcol == 0) {
            #pragma unroll
            for (int r = 0; r < 4; ++r) scp[w][mt * 16 + quad * 4 + r] = part[r];
        }
    }
    __syncthreads();

    if (t < 128) {
        float s = 0.f;
        #pragma unroll
        for (int ww = 0; ww < 8; ++ww) s += scp[ww][t];
        sc[t] = tanhf(s);
    }
    __syncthreads();

    if (t < 32) {
        float s0 = sc[t], s1 = sc[32 + t], s2 = sc[64 + t], s3 = sc[96 + t];
        float m = fmaxf(fmaxf(s0, s1), fmaxf(s2, s3));
        float e0 = expf(s0 - m), e1 = expf(s1 - m), e2 = expf(s2 - m), e3 = expf(s3 - m);
        float inv = 1.f / (e0 + e1 + e2 + e3);
        al[0][t] = e0 * inv; al[1][t] = e1 * inv; al[2][t] = e2 * inv; al[3][t] = e3 * inv;
    }
    __syncthreads();

    {
        int bl = t >> 4, e0 = (t & 15) * 8;
        float a0 = al[0][bl], a1 = al[1][bl], a2 = al[2][bl], a3 = al[3][bl];
        ushort_t outv[8];
        #pragma unroll
        for (int j = 0; j < 8; ++j) {
            int e = e0 + j;
            float v = a0 * b2f(chs[(0 * 32 + bl) * 136 + e])
                    + a1 * b2f(chs[(1 * 32 + bl) * 136 + e])
                    + a2 * b2f(chs[(2 * 32 + bl) * 136 + e])
                    + a3 * b2f(chs[(3 * 32 + bl) * 136 + e]);
            outv[j] = f2b(v);
        }
        *(s8*)(h0out + (size_t)(pbase + bl) * 128 + e0) = *(const s8*)outv;
    }
}

// ---------------------------------------------------------------------------
// Per-level partial max: grid (128, 8); block y covers a node chunk, writes
// fp32 partial (or -inf for empty chunks) to pmax[y][32768].
// ---------------------------------------------------------------------------
__global__ __launch_bounds__(256) void max_part(
    const ushort_t* __restrict__ h, int nodes, float* __restrict__ pmax)
{
    int e = blockIdx.x * 256 + threadIdx.x;     // 0..32767
    int y = blockIdx.y;
    int cn = (nodes + 7) >> 3;
    int n0 = y * cn, n1 = min(nodes, n0 + cn);
    float v = -INFINITY;
    #pragma unroll 4
    for (int n = n0; n < n1; ++n)
        v = fmaxf(v, b2f(h[(size_t)n * 32768 + e]));
    pmax[(size_t)y * 32768 + e] = v;
}

// Final: out[e] = max over 48 partial rows (6 levels x 8 chunks).
__global__ __launch_bounds__(256) void final_max(
    const float* __restrict__ pmax, float* __restrict__ out)
{
    int e = blockIdx.x * 256 + threadIdx.x;
    float v = -INFINITY;
    #pragma unroll 8
    for (int r = 0; r < 48; ++r)
        v = fmaxf(v, pmax[(size_t)r * 32768 + e]);
    out[e] = v;
}

extern "C" void kernel_launch(void* const* d_in, const int* in_sizes, int n_in,
                              void* d_out, int out_size, void* d_ws, size_t ws_size,
                              hipStream_t stream)
{
    const int*   tokens = (const int*)d_in[0];
    const float* emb    = (const float*)d_in[1];
    const float* Wih    = (const float*)d_in[2];
    const float* Whh    = (const float*)d_in[3];
    const float* bih    = (const float*)d_in[4];
    const float* bhh    = (const float*)d_in[5];
    const float* SW     = (const float*)d_in[6];
    const float* sb     = (const float*)d_in[7];
    const float* cw     = (const float*)d_in[8];
    float* out = (float*)d_out;

    // ws layout
    ushort_t* embb = (ushort_t*)d_ws;                          // 12.8 MB
    ushort_t* wihb = embb + (size_t)EMB_N;
    ushort_t* whhb = wihb + W_N;
    ushort_t* swtb = whhb + W_N;
    ushort_t* bufA = swtb + SW_N;                              // 67.1 MB (levels 5,3,1)
    ushort_t* bufB = bufA + (size_t)262144 * 128;              // 16.8 MB (levels 4,2,0)
    ushort_t* h0b  = bufB + (size_t)65536 * 128;               // 16.8 MB
    float*    pmax = (float*)(h0b + (size_t)65536 * 128);      // 48*32768*4 = 6.3 MB

    const int starts[6] = {0, 1, 5, 21, 85, 341};
    const int nsz[6]    = {1, 4, 16, 64, 256, 1024};
    ushort_t* buf[6];
    for (int d = 0; d < 6; ++d) buf[d] = ((5 - d) & 1) ? bufB : bufA;

    cvt_kernel<<<(CVT_N / 4 + 255) / 256, 256, 0, stream>>>(
        emb, Wih, Whh, SW, embb, wihb, whhb, swtb);

    // leaf level d=5 (h0 = 0)
    {
        int rows = nsz[5] * BSZ;
        gru_mfma<false><<<rows / 128, 512, 0, stream>>>(
            tokens, embb, wihb, whhb, bih, bhh, nullptr, buf[5], starts[5]);
        max_part<<<dim3(128, 8), 256, 0, stream>>>(buf[5], nsz[5], pmax + (size_t)5 * 8 * 32768);
    }
    // internal levels d=4..0
    for (int d = 4; d >= 0; --d) {
        int rows = nsz[d] * BSZ;
        attn_mfma<<<rows / 32, 512, 0, stream>>>(buf[d + 1], h0b, swtb, sb, cw);
        gru_mfma<true><<<rows / 128, 512, 0, stream>>>(
            tokens, embb, wihb, whhb, bih, bhh, h0b, buf[d], starts[d]);
        max_part<<<dim3(128, 8), 256, 0, stream>>>(buf[d], nsz[d], pmax + (size_t)d * 8 * 32768);
    }
    final_max<<<128, 256, 0, stream>>>(pmax, out);
}

// Round 4
// 294.174 us; speedup vs baseline: 6.6432x; 1.3879x over previous
//
#include <hip/hip_runtime.h>
#include <math.h>

#define BSZ 256
#define ENC 128

typedef short s8 __attribute__((ext_vector_type(8)));   // 8 bf16 in 4 VGPRs
typedef float f4 __attribute__((ext_vector_type(4)));   // MFMA 16x16 acc
typedef unsigned short ushort_t;

__device__ __forceinline__ float fexp2f(float x) { return __builtin_amdgcn_exp2f(x); }
__device__ __forceinline__ float frcpf(float x)  { return __builtin_amdgcn_rcpf(x); }
// fast sigmoid: rcp(1+2^(-x*log2e)); x->-inf: rcp(inf)=0, x->+inf: rcp(1)=1
__device__ __forceinline__ float sigf(float x) {
    return frcpf(1.f + fexp2f(x * -1.44269504f));
}
// fast tanh, NaN-safe at +-inf: 1 - 2*rcp(2^(2x*log2e)+1)
__device__ __forceinline__ float tanh_f(float x) {
    float e = fexp2f(x * 2.88539008f);
    return 1.f - 2.f * frcpf(e + 1.f);
}

__device__ __forceinline__ ushort_t f2b(float f) {
    unsigned u = __float_as_uint(f);
    u = (u + 0x7FFF + ((u >> 16) & 1)) >> 16;   // RNE
    return (ushort_t)u;
}
__device__ __forceinline__ float b2f(ushort_t b) {
    return __uint_as_float(((unsigned)b) << 16);
}

// ---------------------------------------------------------------------------
// Convert emb / Wih / Whh / SW^T to bf16, 4 elems/thread.
// ---------------------------------------------------------------------------
#define EMB_N   6400000          // 50000*128
#define W_N     49152            // 384*128
#define SW_N    16384            // 128*128
#define CVT_N   (EMB_N + 2 * W_N + SW_N)

__global__ __launch_bounds__(256) void cvt_kernel(
    const float* __restrict__ emb, const float* __restrict__ wih,
    const float* __restrict__ whh, const float* __restrict__ sw,
    ushort_t* __restrict__ embb, ushort_t* __restrict__ wihb,
    ushort_t* __restrict__ whhb, ushort_t* __restrict__ swtb)
{
    int i = (blockIdx.x * 256 + threadIdx.x) * 4;
    if (i >= CVT_N) return;
    if (i < EMB_N) {
        float4 v = *(const float4*)(emb + i);
        short4 o; o.x = f2b(v.x); o.y = f2b(v.y); o.z = f2b(v.z); o.w = f2b(v.w);
        *(short4*)(embb + i) = o;
    } else if (i < EMB_N + W_N) {
        int j = i - EMB_N;
        float4 v = *(const float4*)(wih + j);
        short4 o; o.x = f2b(v.x); o.y = f2b(v.y); o.z = f2b(v.z); o.w = f2b(v.w);
        *(short4*)(wihb + j) = o;
    } else if (i < EMB_N + 2 * W_N) {
        int j = i - EMB_N - W_N;
        float4 v = *(const float4*)(whh + j);
        short4 o; o.x = f2b(v.x); o.y = f2b(v.y); o.z = f2b(v.z); o.w = f2b(v.w);
        *(short4*)(whhb + j) = o;
    } else {
        int j = i - EMB_N - 2 * W_N;
        int f = j >> 7, e0 = j & 127;
        short4 o;
        o.x = f2b(sw[(e0 + 0) * 128 + f]);
        o.y = f2b(sw[(e0 + 1) * 128 + f]);
        o.z = f2b(sw[(e0 + 2) * 128 + f]);
        o.w = f2b(sw[(e0 + 3) * 128 + f]);
        *(short4*)(swtb + j) = o;        // SWt[f][e]
    }
}

// ---------------------------------------------------------------------------
// GRU step. Block = 512 thr (8 waves), 128 rows (8 M-tiles). Wave w owns gate
// cols w*16..+15 for all 3 gates; W fragments pinned in VGPRs for the whole
// block (launch_bounds(512,2) -> 256-VGPR budget so they actually stay).
// Operand-swapped MFMA: D = W_frag x X_frag -> lane holds 4 CONSECUTIVE cols
// (g0 = w*16+quad*4) of row (mt*16 + lane&15): 8B vector h0 loads + h stores.
// ---------------------------------------------------------------------------
template <bool HAS_H0>
__global__ __launch_bounds__(512, 2) void gru_mfma(
    const int* __restrict__ tokens, const ushort_t* __restrict__ embb,
    const ushort_t* __restrict__ wihb, const ushort_t* __restrict__ whhb,
    const float* __restrict__ bih, const float* __restrict__ bhh,
    const ushort_t* __restrict__ h0buf, ushort_t* __restrict__ hbuf,
    int lvl_start)
{
    __shared__ ushort_t xs[128 * 136];   // stride 136: conflict-light b128
    __shared__ ushort_t hs[HAS_H0 ? 128 * 136 : 8];

    const int t = threadIdx.x;
    const int base = blockIdx.x * 128;

    // stage x (and h0): 4 threads per row, 32 shorts each
    {
        int rl = t >> 2, c0 = (t & 3) * 32;
        int row = base + rl;
        int tok = tokens[(lvl_start + (row >> 8)) * BSZ + (row & 255)];
        const ushort_t* src = embb + (size_t)tok * 128 + c0;
        ushort_t* dst = &xs[rl * 136 + c0];
        #pragma unroll
        for (int i = 0; i < 4; ++i) *(s8*)(dst + 8 * i) = *(const s8*)(src + 8 * i);
        if (HAS_H0) {
            const ushort_t* hsrc = h0buf + (size_t)row * 128 + c0;
            ushort_t* hdst = &hs[rl * 136 + c0];
            #pragma unroll
            for (int i = 0; i < 4; ++i) *(s8*)(hdst + 8 * i) = *(const s8*)(hsrc + 8 * i);
        }
    }

    const int lane = t & 63, w = t >> 6;
    const int quad = lane >> 4, l15 = lane & 15;
    const int gA = w * 16 + l15;          // W row (gate col) this lane supplies (A operand)
    const int g0 = w * 16 + quad * 4;     // epilogue col group (D m-index)

    // W fragments in registers, loaded once per block.
    // A-operand layout: A[m=lane&15][k = s*32 + quad*8 + j]
    s8 bwi[3][4], bwh[3][4];
    #pragma unroll
    for (int gm = 0; gm < 3; ++gm) {
        const ushort_t* wp = wihb + (size_t)(gm * 128 + gA) * 128 + quad * 8;
        #pragma unroll
        for (int s = 0; s < 4; ++s) bwi[gm][s] = *(const s8*)(wp + 32 * s);
    }
    if (HAS_H0) {
        #pragma unroll
        for (int gm = 0; gm < 3; ++gm) {
            const ushort_t* wp = whhb + (size_t)(gm * 128 + gA) * 128 + quad * 8;
            #pragma unroll
            for (int s = 0; s < 4; ++s) bwh[gm][s] = *(const s8*)(wp + 32 * s);
        }
    }

    float bR[4], bZ[4], biN[4], bhN[4];
    {
        float4 a = *(const float4*)(bih + g0);
        float4 b = *(const float4*)(bhh + g0);
        bR[0] = a.x + b.x; bR[1] = a.y + b.y; bR[2] = a.z + b.z; bR[3] = a.w + b.w;
        float4 c = *(const float4*)(bih + 128 + g0);
        float4 d = *(const float4*)(bhh + 128 + g0);
        bZ[0] = c.x + d.x; bZ[1] = c.y + d.y; bZ[2] = c.z + d.z; bZ[3] = c.w + d.w;
        float4 e = *(const float4*)(bih + 256 + g0);
        float4 f = *(const float4*)(bhh + 256 + g0);
        biN[0] = e.x; biN[1] = e.y; biN[2] = e.z; biN[3] = e.w;
        bhN[0] = f.x; bhN[1] = f.y; bhN[2] = f.z; bhN[3] = f.w;
    }

    __syncthreads();

    #pragma unroll 1
    for (int mt = 0; mt < 8; ++mt) {
        const int row = mt * 16 + l15;    // B-operand n-index == output row
        s8 ax[4], ah[4];
        {
            const ushort_t* ap = &xs[row * 136 + quad * 8];
            #pragma unroll
            for (int s = 0; s < 4; ++s) ax[s] = *(const s8*)(ap + 32 * s);
            if (HAS_H0) {
                const ushort_t* hp = &hs[row * 136 + quad * 8];
                #pragma unroll
                for (int s = 0; s < 4; ++s) ah[s] = *(const s8*)(hp + 32 * s);
            }
        }

        f4 accR = (f4)0.f, accZ = (f4)0.f, accN = (f4)0.f, accNh = (f4)0.f;
        #pragma unroll
        for (int s = 0; s < 4; ++s) {
            accR = __builtin_amdgcn_mfma_f32_16x16x32_bf16(bwi[0][s], ax[s], accR, 0, 0, 0);
            accZ = __builtin_amdgcn_mfma_f32_16x16x32_bf16(bwi[1][s], ax[s], accZ, 0, 0, 0);
            accN = __builtin_amdgcn_mfma_f32_16x16x32_bf16(bwi[2][s], ax[s], accN, 0, 0, 0);
        }
        if (HAS_H0) {
            #pragma unroll
            for (int s = 0; s < 4; ++s) {
                accR  = __builtin_amdgcn_mfma_f32_16x16x32_bf16(bwh[0][s], ah[s], accR, 0, 0, 0);
                accZ  = __builtin_amdgcn_mfma_f32_16x16x32_bf16(bwh[1][s], ah[s], accZ, 0, 0, 0);
                accNh = __builtin_amdgcn_mfma_f32_16x16x32_bf16(bwh[2][s], ah[s], accNh, 0, 0, 0);
            }
        }

        // epilogue: 4 consecutive cols (g0..g0+3) of `row`
        float h0v[4] = {0.f, 0.f, 0.f, 0.f};
        if (HAS_H0) {
            short4 h04 = *(const short4*)&hs[row * 136 + g0];
            h0v[0] = b2f((ushort_t)h04.x); h0v[1] = b2f((ushort_t)h04.y);
            h0v[2] = b2f((ushort_t)h04.z); h0v[3] = b2f((ushort_t)h04.w);
        }
        ushort_t ov[4];
        #pragma unroll
        for (int r = 0; r < 4; ++r) {
            float rr = sigf(accR[r] + bR[r]);
            float zz = sigf(accZ[r] + bZ[r]);
            float hn = HAS_H0 ? (accNh[r] + bhN[r]) : bhN[r];
            float nn = tanh_f(accN[r] + biN[r] + rr * hn);
            float h = nn + zz * (h0v[r] - nn);
            ov[r] = f2b(h);
        }
        *(short4*)(hbuf + (size_t)(base + row) * 128 + g0) = *(const short4*)ov;
    }
}

// ---------------------------------------------------------------------------
// Attention. Block = 512 thr, 32 parents (128 child rows). Operand-swapped:
// lane holds u for 4 consecutive f-cols of one child row; quad-reduce via
// 2 shfl_xor; cross-wave sum in LDS; softmax over k; vectorized h0 epilogue.
// ---------------------------------------------------------------------------
__global__ __launch_bounds__(512, 2) void attn_mfma(
    const ushort_t* __restrict__ hch, ushort_t* __restrict__ h0out,
    const ushort_t* __restrict__ swt, const float* __restrict__ sb,
    const float* __restrict__ cw)
{
    __shared__ ushort_t chs[128 * 136];
    __shared__ float scp[8][128];
    __shared__ float sc[128];
    __shared__ float al[4][32];

    const int t = threadIdx.x;
    const int pbase = blockIdx.x * 32;
    const int pnode = pbase >> 8;
    const int b0 = pbase & 255;

    // stage 128 child rows (k-major: lr = k*32 + bl)
    {
        int lr = t >> 2, c0 = (t & 3) * 32;
        int k = lr >> 5, bl = lr & 31;
        const ushort_t* src = hch + ((size_t)(4 * pnode + k) * BSZ + b0 + bl) * 128 + c0;
        ushort_t* dst = &chs[lr * 136 + c0];
        #pragma unroll
        for (int i = 0; i < 4; ++i) *(s8*)(dst + 8 * i) = *(const s8*)(src + 8 * i);
    }

    const int lane = t & 63, w = t >> 6;
    const int quad = lane >> 4, l15 = lane & 15;
    const int fA = w * 16 + l15;
    const int f0 = w * 16 + quad * 4;

    s8 bsw[4];
    {
        const ushort_t* wp = swt + (size_t)fA * 128 + quad * 8;
        #pragma unroll
        for (int s = 0; s < 4; ++s) bsw[s] = *(const s8*)(wp + 32 * s);
    }
    float sb4[4], cw4[4];
    {
        float4 a = *(const float4*)(sb + f0);
        float4 b = *(const float4*)(cw + f0);
        sb4[0] = a.x; sb4[1] = a.y; sb4[2] = a.z; sb4[3] = a.w;
        cw4[0] = b.x; cw4[1] = b.y; cw4[2] = b.z; cw4[3] = b.w;
    }
    __syncthreads();

    #pragma unroll 1
    for (int mt = 0; mt < 8; ++mt) {
        const int crow = mt * 16 + l15;
        s8 a[4];
        const ushort_t* ap = &chs[crow * 136 + quad * 8];
        #pragma unroll
        for (int s = 0; s < 4; ++s) a[s] = *(const s8*)(ap + 32 * s);

        f4 acc = (f4)0.f;
        #pragma unroll
        for (int s = 0; s < 4; ++s)
            acc = __builtin_amdgcn_mfma_f32_16x16x32_bf16(bsw[s], a[s], acc, 0, 0, 0);

        float part = 0.f;
        #pragma unroll
        for (int r = 0; r < 4; ++r)
            part += tanh_f(acc[r] + sb4[r]) * cw4[r];
        part += __shfl_xor(part, 16);
        part += __shfl_xor(part, 32);
        if (quad == 0) scp[w][mt * 16 + l15] = part;
    }
    __syncthreads();

    if (t < 128) {
        float s = 0.f;
        #pragma unroll
        for (int ww = 0; ww < 8; ++ww) s += scp[ww][t];
        sc[t] = tanh_f(s);
    }
    __syncthreads();

    if (t < 32) {
        float s0 = sc[t], s1 = sc[32 + t], s2 = sc[64 + t], s3 = sc[96 + t];
        float m = fmaxf(fmaxf(s0, s1), fmaxf(s2, s3));
        float e0 = fexp2f((s0 - m) * 1.44269504f), e1 = fexp2f((s1 - m) * 1.44269504f);
        float e2 = fexp2f((s2 - m) * 1.44269504f), e3 = fexp2f((s3 - m) * 1.44269504f);
        float inv = frcpf(e0 + e1 + e2 + e3);
        al[0][t] = e0 * inv; al[1][t] = e1 * inv; al[2][t] = e2 * inv; al[3][t] = e3 * inv;
    }
    __syncthreads();

    {
        int bl = t >> 4, e0 = (t & 15) * 8;
        float a0 = al[0][bl], a1 = al[1][bl], a2 = al[2][bl], a3 = al[3][bl];
        s8 c0v = *(const s8*)&chs[(0 * 32 + bl) * 136 + e0];
        s8 c1v = *(const s8*)&chs[(1 * 32 + bl) * 136 + e0];
        s8 c2v = *(const s8*)&chs[(2 * 32 + bl) * 136 + e0];
        s8 c3v = *(const s8*)&chs[(3 * 32 + bl) * 136 + e0];
        ushort_t ov[8];
        #pragma unroll
        for (int j = 0; j < 8; ++j) {
            float v = a0 * b2f((ushort_t)c0v[j]) + a1 * b2f((ushort_t)c1v[j])
                    + a2 * b2f((ushort_t)c2v[j]) + a3 * b2f((ushort_t)c3v[j]);
            ov[j] = f2b(v);
        }
        *(s8*)(h0out + (size_t)(pbase + bl) * 128 + e0) = *(const s8*)ov;
    }
}

// ---------------------------------------------------------------------------
// Partial max over ALL 1365 nodes (hall buffer): grid (16, CHUNKS).
// ---------------------------------------------------------------------------
#define MAX_CHUNKS 16
__global__ __launch_bounds__(256) void max_part(
    const ushort_t* __restrict__ h, int nodes, float* __restrict__ pmax)
{
    int e0 = (blockIdx.x * 256 + threadIdx.x) * 8;    // 0..32760
    int y = blockIdx.y;
    int cn = (nodes + MAX_CHUNKS - 1) / MAX_CHUNKS;
    int n0 = y * cn, n1 = min(nodes, n0 + cn);
    float v[8];
    #pragma unroll
    for (int j = 0; j < 8; ++j) v[j] = -INFINITY;
    for (int n = n0; n < n1; ++n) {
        s8 hv = *(const s8*)(h + (size_t)n * 32768 + e0);
        #pragma unroll
        for (int j = 0; j < 8; ++j) v[j] = fmaxf(v[j], b2f((ushort_t)hv[j]));
    }
    float* p = pmax + (size_t)y * 32768 + e0;
    #pragma unroll
    for (int j = 0; j < 8; ++j) p[j] = v[j];
}

__global__ __launch_bounds__(256) void final_max(
    const float* __restrict__ pmax, float* __restrict__ out)
{
    int e = blockIdx.x * 256 + threadIdx.x;
    float v = -INFINITY;
    #pragma unroll
    for (int r = 0; r < MAX_CHUNKS; ++r)
        v = fmaxf(v, pmax[(size_t)r * 32768 + e]);
    out[e] = v;
}

extern "C" void kernel_launch(void* const* d_in, const int* in_sizes, int n_in,
                              void* d_out, int out_size, void* d_ws, size_t ws_size,
                              hipStream_t stream)
{
    const int*   tokens = (const int*)d_in[0];
    const float* emb    = (const float*)d_in[1];
    const float* Wih    = (const float*)d_in[2];
    const float* Whh    = (const float*)d_in[3];
    const float* bih    = (const float*)d_in[4];
    const float* bhh    = (const float*)d_in[5];
    const float* SW     = (const float*)d_in[6];
    const float* sb     = (const float*)d_in[7];
    const float* cw     = (const float*)d_in[8];
    float* out = (float*)d_out;

    // ws layout: emb 12.8MB | W 0.2MB | hall (all levels) 89.4MB | h0 16.8MB | pmax 2MB
    ushort_t* embb = (ushort_t*)d_ws;
    ushort_t* wihb = embb + (size_t)EMB_N;
    ushort_t* whhb = wihb + W_N;
    ushort_t* swtb = whhb + W_N;
    ushort_t* hall = swtb + SW_N;
    ushort_t* h0b  = hall + (size_t)1365 * 32768;
    float*    pmax = (float*)(h0b + (size_t)65536 * 128);

    const int starts[6] = {0, 1, 5, 21, 85, 341};
    const int nsz[6]    = {1, 4, 16, 64, 256, 1024};

    cvt_kernel<<<(CVT_N / 4 + 255) / 256, 256, 0, stream>>>(
        emb, Wih, Whh, SW, embb, wihb, whhb, swtb);

    // leaf level d=5 (h0 = 0)
    {
        int rows = nsz[5] * BSZ;
        gru_mfma<false><<<rows / 128, 512, 0, stream>>>(
            tokens, embb, wihb, whhb, bih, bhh, nullptr,
            hall + (size_t)starts[5] * 32768, starts[5]);
    }
    // internal levels d=4..0
    for (int d = 4; d >= 0; --d) {
        int rows = nsz[d] * BSZ;
        attn_mfma<<<rows / 32, 512, 0, stream>>>(
            hall + (size_t)starts[d + 1] * 32768, h0b, swtb, sb, cw);
        gru_mfma<true><<<rows / 128, 512, 0, stream>>>(
            tokens, embb, wihb, whhb, bih, bhh, h0b,
            hall + (size_t)starts[d] * 32768, starts[d]);
    }
    max_part<<<dim3(16, MAX_CHUNKS), 256, 0, stream>>>(hall, 1365, pmax);
    final_max<<<128, 256, 0, stream>>>(pmax, out);
}